// Round 11
// baseline (110.955 us; speedup 1.0000x reference)
//
#include <hip/hip_runtime.h>

constexpr int N_NODES_C = 100000;
constexpr int N_EDGES_C = 1600000;
constexpr int F_IN_C = 64;
constexpr int HEADS_C = 4;
constexpr int F_OUT_C = 16;
constexpr float NEG_SLOPE_C = 0.2f;

constexpr int BUCK_SHIFT = 8;                 // 256 nodes per bucket
constexpr int BUCK_NODES = 1 << BUCK_SHIFT;   // 256
constexpr int NBUCK = (N_NODES_C + BUCK_NODES - 1) / BUCK_NODES;  // 391
constexpr int BUCK_CAP = 5120;                // mean 4096, +16 sigma
constexpr int PART_BLOCKS = 256;
constexpr int EDGES_PER_PART_BLOCK = (N_EDGES_C + PART_BLOCKS - 1) / PART_BLOCKS;  // 6250

typedef __attribute__((ext_vector_type(8))) short short8v;  // 8 bf16 (4 VGPR)
typedef __attribute__((ext_vector_type(4))) float f32x4;    // MFMA accumulator

// round-to-nearest-even fp32 -> bf16 (values are finite; no NaN handling)
static __device__ __forceinline__ unsigned short f2bf(float f)
{
    const unsigned u = __float_as_uint(f);
    return (unsigned short)((u + 0x7FFF + ((u >> 16) & 1)) >> 16);
}
static __device__ __forceinline__ float bf2f(unsigned short b)
{
    return __uint_as_float(((unsigned)b) << 16);
}

// ---------------------------------------------------------------------------
// Kernel 0: prep. Zero bucket cursors; pack W into the MFMA B-fragment
// layout (Bpack, 64x64); pack Wa columns (W·a_src | W·a_dst) into a second
// B-tile (Bpack2) so the logit reduction is done by MFMA in k_project.
// ---------------------------------------------------------------------------
__global__ __launch_bounds__(256) void k_prep(
    const float* __restrict__ W, const float* __restrict__ a_src,
    const float* __restrict__ a_dst, int* __restrict__ bucket_cursor,
    unsigned short* __restrict__ Bpack, unsigned short* __restrict__ Bpack2)
{
    __shared__ float sW[HEADS_C * F_IN_C * F_OUT_C];  // 16 KB
    __shared__ float sA[2 * HEADS_C * F_OUT_C];       // 512 B
    const int t = threadIdx.x;
    for (int i = t; i < NBUCK; i += 256) bucket_cursor[i] = 0;
    for (int i = t; i < HEADS_C * F_IN_C * F_OUT_C; i += 256) sW[i] = W[i];
    if (t < HEADS_C * F_OUT_C) { sA[t] = a_src[t]; sA[64 + t] = a_dst[t]; }
    __syncthreads();

    // main projection B-tile: B[k][n'] = W[n'>>4][k][n'&15]
    for (int idx = t; idx < 4096; idx += 256) {
        const int j    = idx & 7;
        const int lane = (idx >> 3) & 63;
        const int nt   = (idx >> 9) & 3;
        const int kc   = (idx >> 11) & 1;
        const int col  = nt * 16 + (lane & 15);
        const int k    = kc * 32 + (lane >> 4) * 8 + j;
        Bpack[idx] = f2bf(sW[(col >> 4) * 1024 + k * 16 + (col & 15)]);
    }
    // logit B-tile: cols 0-3 = heads (a_src), cols 4-7 = heads (a_dst)
    for (int idx = t; idx < 1024; idx += 256) {
        const int j    = idx & 7;
        const int lane = (idx >> 3) & 63;
        const int kc   = (idx >> 9) & 1;
        const int col  = lane & 15;
        const int k    = kc * 32 + (lane >> 4) * 8 + j;
        float v = 0.f;
        if (col < 8) {
            const int hd = col & 3;
            const float* wrow = &sW[hd * 1024 + k * 16];
            const float* av   = &sA[(col < 4 ? 0 : 64) + hd * 16];
            #pragma unroll
            for (int o = 0; o < 16; ++o) v = fmaf(wrow[o], av[o], v);
        }
        Bpack2[idx] = f2bf(v);
    }
}

// ---------------------------------------------------------------------------
// Kernel 1: projection via MFMA; logits also via MFMA. 10 MFMAs/wave.
// C/D layout: col=lane&15, row=(lane>>4)*4+i.
// ---------------------------------------------------------------------------
__global__ __launch_bounds__(256) void k_project(
    const float* __restrict__ x, const unsigned short* __restrict__ Bpack,
    const unsigned short* __restrict__ Bpack2,
    unsigned short* __restrict__ h, float* __restrict__ ls, float* __restrict__ ld)
{
    const int wid  = threadIdx.x >> 6;
    const int lane = threadIdx.x & 63;
    const int node0 = (blockIdx.x * 4 + wid) * 16;
    const int colg = lane & 15;
    const int kg   = lane >> 4;

    const int rowc = min(node0 + colg, N_NODES_C - 1);
    short8v afrag[2];
    #pragma unroll
    for (int kc = 0; kc < 2; ++kc) {
        const float4* xp = (const float4*)&x[(size_t)rowc * 64 + kc * 32 + kg * 8];
        const float4 q0 = xp[0];
        const float4 q1 = xp[1];
        afrag[kc][0] = (short)f2bf(q0.x); afrag[kc][1] = (short)f2bf(q0.y);
        afrag[kc][2] = (short)f2bf(q0.z); afrag[kc][3] = (short)f2bf(q0.w);
        afrag[kc][4] = (short)f2bf(q1.x); afrag[kc][5] = (short)f2bf(q1.y);
        afrag[kc][6] = (short)f2bf(q1.z); afrag[kc][7] = (short)f2bf(q1.w);
    }

    f32x4 acc[4] = {{0.f,0.f,0.f,0.f},{0.f,0.f,0.f,0.f},
                    {0.f,0.f,0.f,0.f},{0.f,0.f,0.f,0.f}};
    f32x4 accL = {0.f,0.f,0.f,0.f};
    #pragma unroll
    for (int kc = 0; kc < 2; ++kc) {
        #pragma unroll
        for (int nt = 0; nt < 4; ++nt) {
            const short8v bfrag = *(const short8v*)&Bpack[((kc * 4 + nt) * 64 + lane) * 8];
            acc[nt] = __builtin_amdgcn_mfma_f32_16x16x32_bf16(afrag[kc], bfrag, acc[nt], 0, 0, 0);
        }
        const short8v bfrag2 = *(const short8v*)&Bpack2[(kc * 64 + lane) * 8];
        accL = __builtin_amdgcn_mfma_f32_16x16x32_bf16(afrag[kc], bfrag2, accL, 0, 0, 0);
    }

    #pragma unroll
    for (int nt = 0; nt < 4; ++nt) {
        #pragma unroll
        for (int i = 0; i < 4; ++i) {
            const int node = node0 + kg * 4 + i;
            if (node < N_NODES_C)
                h[(size_t)node * 64 + nt * 16 + colg] = f2bf(acc[nt][i]);
        }
    }
    #pragma unroll
    for (int i = 0; i < 4; ++i) {
        const int node = node0 + kg * 4 + i;
        if (node < N_NODES_C) {
            if (colg < 4)      ls[node * HEADS_C + colg]       = accL[i];
            else if (colg < 8) ld[node * HEADS_C + (colg - 4)] = accL[i];
        }
    }
}

// ---------------------------------------------------------------------------
// Kernel 2 (phase A): partition edges into 391 dst-buckets. 1024 threads.
// Single global pass — edges staged in LDS during the histogram pass.
// ---------------------------------------------------------------------------
__global__ __launch_bounds__(1024) void k_partition(
    const int* __restrict__ src, const int* __restrict__ dst,
    int* __restrict__ bucket_cursor, int* __restrict__ bucketed)
{
    __shared__ int cnt[NBUCK];
    __shared__ int base[NBUCK];
    __shared__ unsigned spack[EDGES_PER_PART_BLOCK];        // 25 KB
    __shared__ unsigned short sbuck[EDGES_PER_PART_BLOCK];  // 12.5 KB
    const int t = threadIdx.x;
    for (int i = t; i < NBUCK; i += 1024) cnt[i] = 0;
    __syncthreads();
    const int e0 = blockIdx.x * EDGES_PER_PART_BLOCK;
    const int nE = min(EDGES_PER_PART_BLOCK, N_EDGES_C - e0);
    for (int e = t; e < nE; e += 1024) {
        const int d = dst[e0 + e];
        const int b = d >> BUCK_SHIFT;
        spack[e] = (unsigned)src[e0 + e] | ((unsigned)(d & (BUCK_NODES - 1)) << 17);
        sbuck[e] = (unsigned short)b;
        atomicAdd(&cnt[b], 1);
    }
    __syncthreads();
    for (int i = t; i < NBUCK; i += 1024) {
        base[i] = atomicAdd(&bucket_cursor[i], cnt[i]);
        cnt[i] = 0;                     // reuse as local cursor
    }
    __syncthreads();
    for (int e = t; e < nE; e += 1024) {
        const int b = sbuck[e];
        const int r = atomicAdd(&cnt[b], 1);
        const int p = base[b] + r;
        if (p < BUCK_CAP)
            bucketed[b * BUCK_CAP + p] = (int)spack[e];
    }
}

// ---------------------------------------------------------------------------
// Kernel 3 (merged): one 1024-thread block per bucket. Phase 1 builds the
// bucket's CSR entirely in LDS (hist -> scan -> scatter); phase 2 aggregates
// the bucket's 256 dst nodes (16 waves x 16 nodes each), reading the CSR
// from LDS. No global CSR round-trip, one fewer dispatch.
// ---------------------------------------------------------------------------
__global__ __launch_bounds__(1024) void k_csr_aggregate(
    const int* __restrict__ bucket_cursor, const int* __restrict__ bucketed,
    const float* __restrict__ ls, const float* __restrict__ ld,
    const unsigned short* __restrict__ h, const float* __restrict__ bias,
    float* __restrict__ out)
{
    __shared__ int hist[BUCK_NODES];   // 1 KB  (deg per local node)
    __shared__ int pfx[BUCK_NODES];    // 1 KB  (scan -> cursor -> inclusive)
    __shared__ int stage[BUCK_CAP];    // 20 KB (packed edges)
    __shared__ int csr[BUCK_CAP];      // 20 KB (src per CSR slot)
    const int b = blockIdx.x;
    const int t = threadIdx.x;         // 0..1023
    const int node0 = b * BUCK_NODES;
    const int cnt = min(bucket_cursor[b], BUCK_CAP);
    const int* eb = &bucketed[(size_t)b * BUCK_CAP];

    // ---- phase 1: LDS CSR build ----
    if (t < BUCK_NODES) hist[t] = 0;
    __syncthreads();
    for (int e = t; e < cnt; e += 1024) {
        const int v = eb[e];           // coalesced read
        stage[e] = v;
        atomicAdd(&hist[v >> 17], 1);
    }
    __syncthreads();
    if (t < BUCK_NODES) pfx[t] = hist[t];
    __syncthreads();
    #pragma unroll
    for (int o = 1; o < BUCK_NODES; o <<= 1) {
        int v = 0;
        if (t < BUCK_NODES && t >= o) v = pfx[t - o];
        __syncthreads();
        if (t < BUCK_NODES) pfx[t] += v;
        __syncthreads();
    }
    if (t < BUCK_NODES) pfx[t] -= hist[t];   // exclusive; becomes cursor
    __syncthreads();
    for (int e = t; e < cnt; e += 1024) {
        const int v = stage[e];
        const int r = atomicAdd(&pfx[v >> 17], 1);
        csr[r] = v & 0x1FFFF;
    }
    __syncthreads();                   // pfx[i] now = inclusive prefix

    // ---- phase 2: aggregate (wave wv handles local nodes wv, wv+16, ...) ----
    const int wv   = t >> 6;           // 0..15
    const int lane = t & 63;
    const int hd = lane >> 4;          // my head
    const int jj = lane & 15;          // my edge slot in a 16-chunk
    const int pb = (lane & 48) << 2;   // bpermute byte-base of my head group

    for (int ln = wv; ln < BUCK_NODES; ln += 16) {
        const int d = node0 + ln;
        if (d >= N_NODES_C) continue;
        const int dg    = hist[ln];
        const int start = pfx[ln] - dg;
        const float ldv = ld[d * HEADS_C + hd];

        float acc  = 0.f;
        float denp = 0.f;

        if (dg <= 16) {
            int s_l = 0; float p_l = 0.f;
            if (jj < dg) {
                s_l = csr[start + jj];
                float v = ls[s_l * HEADS_C + hd] + ldv;
                v = (v > 0.f) ? v : v * NEG_SLOPE_C;
                p_l = __expf(v);
            }
            denp = p_l;
            unsigned short hv[16];
            #pragma unroll
            for (int j = 0; j < 16; ++j) {
                const int s_j = __builtin_amdgcn_readlane(s_l, j);
                hv[j] = h[(size_t)(unsigned)s_j * 64 + lane];
            }
            #pragma unroll
            for (int j = 0; j < 16; ++j) {
                const int pi = __builtin_amdgcn_ds_bpermute(pb + (j << 2), __float_as_int(p_l));
                acc = fmaf(__int_as_float(pi), bf2f(hv[j]), acc);
            }
        } else {
            for (int base = 0; base < dg; base += 32) {
                const int rem  = dg - base;
                const int nIn0 = min(16, rem);
                const int nIn1 = min(16, max(0, rem - 16));
                int s0 = 0, s1 = 0; float p0 = 0.f, p1 = 0.f;
                if (jj < nIn0) {
                    s0 = csr[start + base + jj];
                    float v = ls[s0 * HEADS_C + hd] + ldv;
                    v = (v > 0.f) ? v : v * NEG_SLOPE_C;
                    p0 = __expf(v);
                }
                if (jj < nIn1) {
                    s1 = csr[start + base + 16 + jj];
                    float v = ls[s1 * HEADS_C + hd] + ldv;
                    v = (v > 0.f) ? v : v * NEG_SLOPE_C;
                    p1 = __expf(v);
                }
                denp += p0 + p1;
                unsigned short hv0[16], hv1[16];
                #pragma unroll
                for (int j = 0; j < 16; ++j) {
                    const int sj0 = __builtin_amdgcn_readlane(s0, j);
                    hv0[j] = h[(size_t)(unsigned)sj0 * 64 + lane];
                    const int sj1 = __builtin_amdgcn_readlane(s1, j);
                    hv1[j] = h[(size_t)(unsigned)sj1 * 64 + lane];
                }
                #pragma unroll
                for (int j = 0; j < 16; ++j) {
                    const int pi0 = __builtin_amdgcn_ds_bpermute(pb + (j << 2), __float_as_int(p0));
                    acc = fmaf(__int_as_float(pi0), bf2f(hv0[j]), acc);
                    const int pi1 = __builtin_amdgcn_ds_bpermute(pb + (j << 2), __float_as_int(p1));
                    acc = fmaf(__int_as_float(pi1), bf2f(hv1[j]), acc);
                }
            }
        }
        #pragma unroll
        for (int o = 8; o >= 1; o >>= 1) denp += __shfl_xor(denp, o, 64);
        out[(size_t)d * 64 + lane] = acc / (denp + 1e-16f) + bias[lane];
    }
}

extern "C" void kernel_launch(void* const* d_in, const int* in_sizes, int n_in,
                              void* d_out, int out_size, void* d_ws, size_t ws_size,
                              hipStream_t stream)
{
    const float* x     = (const float*)d_in[0];
    const int*   ei    = (const int*)d_in[1];    // [2, E]: row0 = src, row1 = dst
    const float* W     = (const float*)d_in[2];
    const float* a_src = (const float*)d_in[3];
    const float* a_dst = (const float*)d_in[4];
    const float* bias  = (const float*)d_in[5];
    float* out = (float*)d_out;

    // workspace layout
    float* ws   = (float*)d_ws;
    unsigned short* h = (unsigned short*)ws;        // N*64 bf16   (12.8 MB)
    float* ls   = (float*)(h + (size_t)N_NODES_C * 64);  // N*4    (1.6 MB)
    float* ld   = ls + (size_t)N_NODES_C * HEADS_C;      // N*4    (1.6 MB)
    int* bucket_cursor = (int*)(ld + (size_t)N_NODES_C * HEADS_C);  // NBUCK
    int* bucketed = bucket_cursor + NBUCK;          // NBUCK*BUCK_CAP (8.0 MB)
    unsigned short* Bpack  = (unsigned short*)(bucketed + (size_t)NBUCK * BUCK_CAP); // 4096 bf16
    unsigned short* Bpack2 = Bpack + 4096;                                           // 1024 bf16

    const int* src = ei;
    const int* dst = ei + N_EDGES_C;

    k_prep<<<1, 256, 0, stream>>>(W, a_src, a_dst, bucket_cursor, Bpack, Bpack2);
    k_project<<<(N_NODES_C + 63) / 64, 256, 0, stream>>>(x, Bpack, Bpack2, h, ls, ld);
    k_partition<<<PART_BLOCKS, 1024, 0, stream>>>(src, dst, bucket_cursor, bucketed);
    k_csr_aggregate<<<NBUCK, 1024, 0, stream>>>(bucket_cursor, bucketed, ls, ld, h, bias, out);
}

// Round 12
// 99.591 us; speedup vs baseline: 1.1141x; 1.1141x over previous
//
#include <hip/hip_runtime.h>

constexpr int N_NODES_C = 100000;
constexpr int N_EDGES_C = 1600000;
constexpr int F_IN_C = 64;
constexpr int HEADS_C = 4;
constexpr int F_OUT_C = 16;
constexpr float NEG_SLOPE_C = 0.2f;

constexpr int BUCK_SHIFT = 8;                 // 256 nodes per bucket
constexpr int BUCK_NODES = 1 << BUCK_SHIFT;   // 256
constexpr int NBUCK = (N_NODES_C + BUCK_NODES - 1) / BUCK_NODES;  // 391
constexpr int BUCK_CAP = 5120;                // mean 4096, +16 sigma
constexpr int PART_BLOCKS = 256;
constexpr int EDGES_PER_PART_BLOCK = (N_EDGES_C + PART_BLOCKS - 1) / PART_BLOCKS;  // 6250

typedef __attribute__((ext_vector_type(8))) short short8v;  // 8 bf16 (4 VGPR)
typedef __attribute__((ext_vector_type(4))) float f32x4;    // MFMA accumulator

// round-to-nearest-even fp32 -> bf16 (values are finite; no NaN handling)
static __device__ __forceinline__ unsigned short f2bf(float f)
{
    const unsigned u = __float_as_uint(f);
    return (unsigned short)((u + 0x7FFF + ((u >> 16) & 1)) >> 16);
}
static __device__ __forceinline__ float bf2f(unsigned short b)
{
    return __uint_as_float(((unsigned)b) << 16);
}

// ---------------------------------------------------------------------------
// Kernel 1: projection via MFMA; logits also via MFMA. The B-fragment pack
// (formerly k_prep) is now built per-block in LDS from W (16 KB, L2-hot):
// Bpack[k][n'] = W[n'>>4][k][n'&15]; Bpack2 cols 0-3 = W·a_src per head,
// cols 4-7 = W·a_dst. Block 0 also zeroes the bucket cursors (k_partition
// runs later on the stream, so ordering is safe).
// C/D layout: col=lane&15, row=(lane>>4)*4+i.
// ---------------------------------------------------------------------------
__global__ __launch_bounds__(256) void k_project(
    const float* __restrict__ x, const float* __restrict__ W,
    const float* __restrict__ a_src, const float* __restrict__ a_dst,
    int* __restrict__ bucket_cursor,
    unsigned short* __restrict__ h, float* __restrict__ ls, float* __restrict__ ld)
{
    __shared__ float sW[HEADS_C * F_IN_C * F_OUT_C];  // 16 KB
    __shared__ float sA[2 * HEADS_C * F_OUT_C];       // 512 B
    __shared__ unsigned short sBp[4096];              // 8 KB
    __shared__ unsigned short sBp2[1024];             // 2 KB
    const int t = threadIdx.x;

    if (blockIdx.x == 0)
        for (int i = t; i < NBUCK; i += 256) bucket_cursor[i] = 0;

    for (int i = t; i < HEADS_C * F_IN_C * F_OUT_C; i += 256) sW[i] = W[i];
    if (t < 64)       sA[t]      = a_src[t];
    else if (t < 128) sA[t]      = a_dst[t - 64];
    __syncthreads();

    // pack main projection B-tile
    for (int idx = t; idx < 4096; idx += 256) {
        const int j    = idx & 7;
        const int lane = (idx >> 3) & 63;
        const int nt   = (idx >> 9) & 3;
        const int kc   = (idx >> 11) & 1;
        const int col  = nt * 16 + (lane & 15);
        const int k    = kc * 32 + (lane >> 4) * 8 + j;
        sBp[idx] = f2bf(sW[(col >> 4) * 1024 + k * 16 + (col & 15)]);
    }
    // pack logit B-tile
    for (int idx = t; idx < 1024; idx += 256) {
        const int j    = idx & 7;
        const int lane = (idx >> 3) & 63;
        const int kc   = (idx >> 9) & 1;
        const int col  = lane & 15;
        const int k    = kc * 32 + (lane >> 4) * 8 + j;
        float v = 0.f;
        if (col < 8) {
            const int hd = col & 3;
            const float* wrow = &sW[hd * 1024 + k * 16];
            const float* av   = &sA[(col < 4 ? 0 : 64) + hd * 16];
            #pragma unroll
            for (int o = 0; o < 16; ++o) v = fmaf(wrow[o], av[o], v);
        }
        sBp2[idx] = f2bf(v);
    }

    const int wid  = threadIdx.x >> 6;
    const int lane = threadIdx.x & 63;
    const int node0 = (blockIdx.x * 4 + wid) * 16;
    const int colg = lane & 15;
    const int kg   = lane >> 4;

    // A fragments (issued independently of the LDS pack; no barrier needed yet)
    const int rowc = min(node0 + colg, N_NODES_C - 1);
    short8v afrag[2];
    #pragma unroll
    for (int kc = 0; kc < 2; ++kc) {
        const float4* xp = (const float4*)&x[(size_t)rowc * 64 + kc * 32 + kg * 8];
        const float4 q0 = xp[0];
        const float4 q1 = xp[1];
        afrag[kc][0] = (short)f2bf(q0.x); afrag[kc][1] = (short)f2bf(q0.y);
        afrag[kc][2] = (short)f2bf(q0.z); afrag[kc][3] = (short)f2bf(q0.w);
        afrag[kc][4] = (short)f2bf(q1.x); afrag[kc][5] = (short)f2bf(q1.y);
        afrag[kc][6] = (short)f2bf(q1.z); afrag[kc][7] = (short)f2bf(q1.w);
    }
    __syncthreads();

    f32x4 acc[4] = {{0.f,0.f,0.f,0.f},{0.f,0.f,0.f,0.f},
                    {0.f,0.f,0.f,0.f},{0.f,0.f,0.f,0.f}};
    f32x4 accL = {0.f,0.f,0.f,0.f};
    #pragma unroll
    for (int kc = 0; kc < 2; ++kc) {
        #pragma unroll
        for (int nt = 0; nt < 4; ++nt) {
            const short8v bfrag = *(const short8v*)&sBp[((kc * 4 + nt) * 64 + lane) * 8];
            acc[nt] = __builtin_amdgcn_mfma_f32_16x16x32_bf16(afrag[kc], bfrag, acc[nt], 0, 0, 0);
        }
        const short8v bfrag2 = *(const short8v*)&sBp2[(kc * 64 + lane) * 8];
        accL = __builtin_amdgcn_mfma_f32_16x16x32_bf16(afrag[kc], bfrag2, accL, 0, 0, 0);
    }

    #pragma unroll
    for (int nt = 0; nt < 4; ++nt) {
        #pragma unroll
        for (int i = 0; i < 4; ++i) {
            const int node = node0 + kg * 4 + i;
            if (node < N_NODES_C)
                h[(size_t)node * 64 + nt * 16 + colg] = f2bf(acc[nt][i]);
        }
    }
    #pragma unroll
    for (int i = 0; i < 4; ++i) {
        const int node = node0 + kg * 4 + i;
        if (node < N_NODES_C) {
            if (colg < 4)      ls[node * HEADS_C + colg]       = accL[i];
            else if (colg < 8) ld[node * HEADS_C + (colg - 4)] = accL[i];
        }
    }
}

// ---------------------------------------------------------------------------
// Kernel 2 (phase A): partition edges into 391 dst-buckets. 1024 threads.
// Single global pass — edges staged in LDS during the histogram pass.
// ---------------------------------------------------------------------------
__global__ __launch_bounds__(1024) void k_partition(
    const int* __restrict__ src, const int* __restrict__ dst,
    int* __restrict__ bucket_cursor, int* __restrict__ bucketed)
{
    __shared__ int cnt[NBUCK];
    __shared__ int base[NBUCK];
    __shared__ unsigned spack[EDGES_PER_PART_BLOCK];        // 25 KB
    __shared__ unsigned short sbuck[EDGES_PER_PART_BLOCK];  // 12.5 KB
    const int t = threadIdx.x;
    for (int i = t; i < NBUCK; i += 1024) cnt[i] = 0;
    __syncthreads();
    const int e0 = blockIdx.x * EDGES_PER_PART_BLOCK;
    const int nE = min(EDGES_PER_PART_BLOCK, N_EDGES_C - e0);
    for (int e = t; e < nE; e += 1024) {
        const int d = dst[e0 + e];
        const int b = d >> BUCK_SHIFT;
        spack[e] = (unsigned)src[e0 + e] | ((unsigned)(d & (BUCK_NODES - 1)) << 17);
        sbuck[e] = (unsigned short)b;
        atomicAdd(&cnt[b], 1);
    }
    __syncthreads();
    for (int i = t; i < NBUCK; i += 1024) {
        base[i] = atomicAdd(&bucket_cursor[i], cnt[i]);
        cnt[i] = 0;                     // reuse as local cursor
    }
    __syncthreads();
    for (int e = t; e < nE; e += 1024) {
        const int b = sbuck[e];
        const int r = atomicAdd(&cnt[b], 1);
        const int p = base[b] + r;
        if (p < BUCK_CAP)
            bucketed[b * BUCK_CAP + p] = (int)spack[e];
    }
}

// ---------------------------------------------------------------------------
// Kernel 3 (phase B): one 256-thread block per bucket -> CSR segment, off/deg.
// ---------------------------------------------------------------------------
__global__ __launch_bounds__(256) void k_buildcsr(
    const int* __restrict__ bucket_cursor, const int* __restrict__ bucketed,
    int* __restrict__ csr_src, int* __restrict__ off, int* __restrict__ deg)
{
    __shared__ int hist[BUCK_NODES];   // 1 KB (degrees)
    __shared__ int pfx[BUCK_NODES];    // 1 KB (scan buffer, then cursor)
    __shared__ int stageIn[BUCK_CAP];  // 20 KB
    __shared__ int stageOut[BUCK_CAP]; // 20 KB
    const int b = blockIdx.x;
    const int t = threadIdx.x;         // 0..255
    const int node0 = b * BUCK_NODES;
    const int nNodes = min(BUCK_NODES, N_NODES_C - node0);
    const int cnt = min(bucket_cursor[b], BUCK_CAP);
    const int* eb = &bucketed[(size_t)b * BUCK_CAP];

    hist[t] = 0;
    __syncthreads();
    for (int e = t; e < cnt; e += 256) {
        const int v = eb[e];          // coalesced read
        stageIn[e] = v;
        atomicAdd(&hist[v >> 17], 1);
    }
    __syncthreads();
    const int myDeg = hist[t];
    pfx[t] = myDeg;
    __syncthreads();
    #pragma unroll
    for (int o = 1; o < BUCK_NODES; o <<= 1) {
        const int v = (t >= o) ? pfx[t - o] : 0;
        __syncthreads();
        pfx[t] += v;
        __syncthreads();
    }
    const int excl = pfx[t] - myDeg;   // exclusive prefix (own slot only)
    if (t < nNodes) {
        deg[node0 + t] = myDeg;
        off[node0 + t] = b * BUCK_CAP + excl;
    }
    pfx[t] = excl;                     // becomes the scatter cursor
    __syncthreads();
    for (int e = t; e < cnt; e += 256) {
        const int v = stageIn[e];
        const int r = atomicAdd(&pfx[v >> 17], 1);
        stageOut[r] = v & 0x1FFFF;
    }
    __syncthreads();
    int* outp = &csr_src[(size_t)b * BUCK_CAP];
    for (int e = t; e < cnt; e += 256) outp[e] = stageOut[e];
}

// ---------------------------------------------------------------------------
// Kernel 4: per-dst gather-reduce, shift-free softmax, bf16 h,
// degree-specialized, 16/32-wide batched h-loads. R9-proven version.
// ---------------------------------------------------------------------------
__global__ __launch_bounds__(256) void k_aggregate(
    const int* __restrict__ csr_src, const int* __restrict__ off,
    const int* __restrict__ deg, const float* __restrict__ ls,
    const float* __restrict__ ld, const unsigned short* __restrict__ h,
    const float* __restrict__ bias, float* __restrict__ out)
{
    const int wid  = threadIdx.x >> 6;
    const int lane = threadIdx.x & 63;
    const int d = blockIdx.x * 4 + wid;
    if (d >= N_NODES_C) return;
    const int hd = lane >> 4;        // my head
    const int jj = lane & 15;        // my edge slot within a 16-edge chunk
    const int pb = (lane & 48) << 2; // bpermute byte-base of my head group

    const int start = off[d];
    const int dg    = deg[d];
    const float ldv = ld[d * HEADS_C + hd];

    float acc  = 0.f;
    float denp = 0.f;

    if (dg <= 16) {
        int s_l = 0; float p_l = 0.f;
        if (jj < dg) {
            s_l = csr_src[start + jj];
            float v = ls[s_l * HEADS_C + hd] + ldv;
            v = (v > 0.f) ? v : v * NEG_SLOPE_C;
            p_l = __expf(v);
        }
        denp = p_l;
        unsigned short hv[16];
        #pragma unroll
        for (int j = 0; j < 16; ++j) {
            const int s_j = __builtin_amdgcn_readlane(s_l, j);
            hv[j] = h[(size_t)(unsigned)s_j * 64 + lane];
        }
        #pragma unroll
        for (int j = 0; j < 16; ++j) {
            const int pi = __builtin_amdgcn_ds_bpermute(pb + (j << 2), __float_as_int(p_l));
            acc = fmaf(__int_as_float(pi), bf2f(hv[j]), acc);
        }
    } else {
        for (int base = 0; base < dg; base += 32) {
            const int rem  = dg - base;
            const int nIn0 = min(16, rem);
            const int nIn1 = min(16, max(0, rem - 16));
            int s0 = 0, s1 = 0; float p0 = 0.f, p1 = 0.f;
            if (jj < nIn0) {
                s0 = csr_src[start + base + jj];
                float v = ls[s0 * HEADS_C + hd] + ldv;
                v = (v > 0.f) ? v : v * NEG_SLOPE_C;
                p0 = __expf(v);
            }
            if (jj < nIn1) {
                s1 = csr_src[start + base + 16 + jj];
                float v = ls[s1 * HEADS_C + hd] + ldv;
                v = (v > 0.f) ? v : v * NEG_SLOPE_C;
                p1 = __expf(v);
            }
            denp += p0 + p1;
            unsigned short hv0[16], hv1[16];
            #pragma unroll
            for (int j = 0; j < 16; ++j) {
                const int sj0 = __builtin_amdgcn_readlane(s0, j);
                hv0[j] = h[(size_t)(unsigned)sj0 * 64 + lane];
                const int sj1 = __builtin_amdgcn_readlane(s1, j);
                hv1[j] = h[(size_t)(unsigned)sj1 * 64 + lane];
            }
            #pragma unroll
            for (int j = 0; j < 16; ++j) {
                const int pi0 = __builtin_amdgcn_ds_bpermute(pb + (j << 2), __float_as_int(p0));
                acc = fmaf(__int_as_float(pi0), bf2f(hv0[j]), acc);
                const int pi1 = __builtin_amdgcn_ds_bpermute(pb + (j << 2), __float_as_int(p1));
                acc = fmaf(__int_as_float(pi1), bf2f(hv1[j]), acc);
            }
        }
    }
    #pragma unroll
    for (int o = 8; o >= 1; o >>= 1) denp += __shfl_xor(denp, o, 64);
    out[(size_t)d * 64 + lane] = acc / (denp + 1e-16f) + bias[lane];
}

extern "C" void kernel_launch(void* const* d_in, const int* in_sizes, int n_in,
                              void* d_out, int out_size, void* d_ws, size_t ws_size,
                              hipStream_t stream)
{
    const float* x     = (const float*)d_in[0];
    const int*   ei    = (const int*)d_in[1];    // [2, E]: row0 = src, row1 = dst
    const float* W     = (const float*)d_in[2];
    const float* a_src = (const float*)d_in[3];
    const float* a_dst = (const float*)d_in[4];
    const float* bias  = (const float*)d_in[5];
    float* out = (float*)d_out;

    // workspace layout
    float* ws   = (float*)d_ws;
    unsigned short* h = (unsigned short*)ws;        // N*64 bf16   (12.8 MB)
    float* ls   = (float*)(h + (size_t)N_NODES_C * 64);  // N*4    (1.6 MB)
    float* ld   = ls + (size_t)N_NODES_C * HEADS_C;      // N*4    (1.6 MB)
    int* bucket_cursor = (int*)(ld + (size_t)N_NODES_C * HEADS_C);  // NBUCK
    int* deg     = bucket_cursor + NBUCK;           // N
    int* off     = deg + N_NODES_C;                 // N
    int* bucketed = off + N_NODES_C;                // NBUCK*BUCK_CAP (8.0 MB)
    int* csr_src  = bucketed + (size_t)NBUCK * BUCK_CAP;  // NBUCK*BUCK_CAP

    const int* src = ei;
    const int* dst = ei + N_EDGES_C;

    k_project<<<(N_NODES_C + 63) / 64, 256, 0, stream>>>(
        x, W, a_src, a_dst, bucket_cursor, h, ls, ld);
    k_partition<<<PART_BLOCKS, 1024, 0, stream>>>(src, dst, bucket_cursor, bucketed);
    k_buildcsr<<<NBUCK, 256, 0, stream>>>(bucket_cursor, bucketed, csr_src, off, deg);
    k_aggregate<<<(N_NODES_C + 3) / 4, 256, 0, stream>>>(csr_src, off, deg, ls, ld, h, bias, out);
}